// Round 8
// baseline (210.695 us; speedup 1.0000x reference)
//
#include <hip/hip_runtime.h>
#include <cstdint>
#include <cstddef>

#define NN 4096
#define DD 128

using short8 = __attribute__((ext_vector_type(8))) short;
using f32x4  = __attribute__((ext_vector_type(4))) float;
typedef unsigned long long u64;

typedef __attribute__((address_space(1))) void gvoid;
typedef __attribute__((address_space(3))) void lvoid;

__device__ __forceinline__ void async16(const void* g, void* l) {
  __builtin_amdgcn_global_load_lds((gvoid*)g, (lvoid*)l, 16, 0, 0);
}

__device__ __forceinline__ float dec_f(const void* p) {
  if (!p) return 1.0f;
  int b = *(const int*)p;
  return (b >= 0 && b < 1000000) ? (float)b : __int_as_float(b);
}
__device__ __forceinline__ int dec_i(const void* p) {
  if (!p) return 4;
  int b = *(const int*)p;
  return (b >= 0 && b < 1000000) ? b : (int)__int_as_float(b);
}

__device__ __forceinline__ unsigned short f2bf(float f) {
  union { float f; unsigned int u; } v; v.f = f;
  unsigned int u = v.u;
  unsigned int r = (u + 0x7fffu + ((u >> 16) & 1u)) >> 16;
  return (unsigned short)r;
}

// sorted-4 insert of packed key (d2_bits<<32 | idx), ascending; order-invariant result
__device__ __forceinline__ void ins4(u64 (&l)[4], u64 k) {
#pragma unroll
  for (int t = 0; t < 4; ++t) {
    u64 old = l[t];
    bool bt = k < old;
    l[t] = bt ? k : old;
    k = bt ? old : k;
  }
}

// stage ROWS x KC bf16 tile (16B chunks; physical chunk p holds logical p^(r&7))
template <int ROWS, int KC, int NTHR>
__device__ __forceinline__ void stage2(const unsigned short* src, int row0, int kb,
                                       unsigned short* dst, int tid, int stride) {
  const int CPR = KC / 8;
  const int ITER = (ROWS * CPR) / NTHR;
#pragma unroll
  for (int t = 0; t < ITER; ++t) {
    int id = tid + t * NTHR;
    int r = id / CPR;
    int p = id % CPR;
    int lc = p ^ (r & 7);
    const void* g = src + (size_t)(row0 + r) * stride + kb + lc * 8;
    async16(g, dst + (size_t)(id & ~63) * 8);
  }
}

template <int CPR>
__device__ __forceinline__ short8 fragN(const unsigned short* t, int row, int ch) {
  return *(const short8*)(t + (size_t)(row * CPR + (ch ^ (row & 7))) * 8);
}

// ---------------- K1: rowsum(A), d = rsqrt, A -> bf16 ----------------
__global__ __launch_bounds__(256) void k_rowsum_scale(
    const float* __restrict__ A,
    float* __restrict__ rowsumA, float* __restrict__ dvec,
    unsigned short* __restrict__ Ah) {
  int row = blockIdx.x;
  int tid = threadIdx.x;
  const float4* Arow = (const float4*)(A + (size_t)row * NN);
  float s = 0.f;
#pragma unroll
  for (int l = 0; l < 4; ++l) {
    int idx = tid + l * 256;
    float4 v = Arow[idx];
    s += (v.x + v.y) + (v.z + v.w);
    ushort4 h = {f2bf(v.x), f2bf(v.y), f2bf(v.z), f2bf(v.w)};
    *(ushort4*)(Ah + (size_t)row * NN + idx * 4) = h;
  }
  __shared__ float red[256];
  red[tid] = s;
  __syncthreads();
  if (tid < 64) {
    s = red[tid] + red[tid + 64] + red[tid + 128] + red[tid + 192];
#pragma unroll
    for (int off = 32; off > 0; off >>= 1) s += __shfl_down(s, off, 64);
    if (tid == 0) { rowsumA[row] = s; dvec[row] = rsqrtf(s); }
  }
}

// ---- K2/K5: fused [merge->] V=d*x (LDS) -> U=V@W -> UTh bf16 transposed [+ U fp32] ----
// grid 64, 256 thr; MODE 1: pass-1 (dvec given); MODE 2: pass-2 (merge pkeys -> d2)
template <int MODE>
__global__ __launch_bounds__(256) void k_xwt(
    const float* __restrict__ x, const float* __restrict__ W,
    const float* __restrict__ dsrc,
    const u64* __restrict__ pkey, const float* __restrict__ rowsumA,
    float* __restrict__ sval, int* __restrict__ sidx, float* __restrict__ d2vec,
    float* __restrict__ Uout, unsigned short* __restrict__ UTh,
    const void* kptr, const void* sigptr) {
  __shared__ float Vs[64 * 132];   // V rows; reused as Ut[128][64] for the transpose
  __shared__ float Ws[32 * 128];
  __shared__ float dsm[64];
  int bx = blockIdx.x, tid = threadIdx.x;
  int r0 = bx * 64;

  if (MODE == 1) {
    if (tid < 64) dsm[tid] = dsrc[r0 + tid];
  } else {
    if (tid < 64) {
      int r = r0 + tid;
      u64 best[4] = {~0ull, ~0ull, ~0ull, ~0ull};
      for (int p = 0; p < 16; ++p) {
#pragma unroll
        for (int s = 0; s < 4; ++s) ins4(best, pkey[((size_t)r * 16 + p) * 4 + s]);
      }
      int kk = dec_i(kptr); kk = kk < 1 ? 1 : (kk > 4 ? 4 : kk);
      float inv2s = 0.5f / dec_f(sigptr);
      float srw = 0.f;
#pragma unroll
      for (int s = 0; s < 4; ++s) {
        if (s < kk) {
          float d2 = __uint_as_float((unsigned)(best[s] >> 32));
          float S = __expf(-sqrtf(d2 + 1e-10f) * inv2s);
          sval[r * 8 + s] = S;
          sidx[r * 8 + s] = (int)(best[s] & 0xffffffffu);
          srw += S;
        }
      }
      float dd = rsqrtf(rowsumA[r] + srw);
      d2vec[r] = dd;
      dsm[tid] = dd;
    }
  }
  __syncthreads();
  // Vs = d * x rows (same fmul as before)
#pragma unroll
  for (int l = 0; l < 8; ++l) {
    int idx = tid + l * 256;
    int r = idx >> 5, c4 = (idx & 31) << 2;
    float4 xv = *(const float4*)(x + (size_t)(r0 + r) * DD + c4);
    float dd = dsm[r];
    Vs[r * 132 + c4 + 0] = dd * xv.x;
    Vs[r * 132 + c4 + 1] = dd * xv.y;
    Vs[r * 132 + c4 + 2] = dd * xv.z;
    Vs[r * 132 + c4 + 3] = dd * xv.w;
  }

  int tr = tid >> 4, tc = tid & 15;   // 16 row-groups x 16 col-groups; 4 rows, 8 cols each
  float acc[4][8];
#pragma unroll
  for (int rr = 0; rr < 4; ++rr)
#pragma unroll
    for (int u = 0; u < 8; ++u) acc[rr][u] = 0.f;

  for (int t0 = 0; t0 < 128; t0 += 32) {
    __syncthreads();
#pragma unroll
    for (int l = 0; l < 4; ++l) {
      int idx = tid + l * 256;
      int tt = idx >> 5, c4 = (idx & 31) << 2;
      *(float4*)(Ws + tt * 128 + c4) = *(const float4*)(W + (size_t)(t0 + tt) * DD + c4);
    }
    __syncthreads();
#pragma unroll 8
    for (int tt = 0; tt < 32; ++tt) {
      float4 w0 = *(const float4*)(Ws + tt * 128 + tc * 8);
      float4 w1 = *(const float4*)(Ws + tt * 128 + tc * 8 + 4);
#pragma unroll
      for (int rr = 0; rr < 4; ++rr) {
        float g = Vs[(tr * 4 + rr) * 132 + t0 + tt];
        acc[rr][0] = fmaf(g, w0.x, acc[rr][0]); acc[rr][1] = fmaf(g, w0.y, acc[rr][1]);
        acc[rr][2] = fmaf(g, w0.z, acc[rr][2]); acc[rr][3] = fmaf(g, w0.w, acc[rr][3]);
        acc[rr][4] = fmaf(g, w1.x, acc[rr][4]); acc[rr][5] = fmaf(g, w1.y, acc[rr][5]);
        acc[rr][6] = fmaf(g, w1.z, acc[rr][6]); acc[rr][7] = fmaf(g, w1.w, acc[rr][7]);
      }
    }
  }

  if (MODE == 2) {
    // U fp32 rows (for the sparse gather in pass-2 epilogue)
#pragma unroll
    for (int rr = 0; rr < 4; ++rr) {
      size_t off = (size_t)(r0 + tr * 4 + rr) * DD + tc * 8;
      float4 o0 = {acc[rr][0], acc[rr][1], acc[rr][2], acc[rr][3]};
      float4 o1 = {acc[rr][4], acc[rr][5], acc[rr][6], acc[rr][7]};
      *(float4*)(Uout + off) = o0;
      *(float4*)(Uout + off + 4) = o1;
    }
  }
  __syncthreads();   // all Vs reads done; reuse as Ut[c][r]
#pragma unroll
  for (int rr = 0; rr < 4; ++rr)
#pragma unroll
    for (int cc = 0; cc < 8; ++cc)
      Vs[(tc * 8 + cc) * 64 + tr * 4 + rr] = acc[rr][cc];
  __syncthreads();
  {
    int c = tid >> 1, h = tid & 1;
    unsigned short hb[32];
#pragma unroll
    for (int i = 0; i < 32; ++i) hb[i] = f2bf(Vs[c * 64 + h * 32 + i]);
    size_t base = (size_t)c * NN + r0 + h * 32;
#pragma unroll
    for (int q = 0; q < 8; ++q) {
      ushort4 hh = {hb[q * 4], hb[q * 4 + 1], hb[q * 4 + 2], hb[q * 4 + 3]};
      *(ushort4*)(UTh + base + q * 4) = hh;
    }
  }
}

// ---------------- K3: MFMA bf16 GEMM  G_part = A[128 rows][KLEN k] @ U ----------------
template <int SPLIT>
__global__ __launch_bounds__(256) void k_gemm_bf16(
    const unsigned short* __restrict__ Ah, const unsigned short* __restrict__ Bh,
    float* __restrict__ G) {
  __shared__ __align__(16) unsigned short As_h[128 * 64];
  __shared__ __align__(16) unsigned short Bs_h[128 * 64];

  int bx = blockIdx.x;
  int mt = bx / SPLIT, sp = bx % SPLIT;
  int m0 = mt * 128;
  const int KLEN = NN / SPLIT;
  int ks = sp * KLEN;
  int tid = threadIdx.x, lane = tid & 63, w = tid >> 6;
  int wm = w >> 1, wn = w & 1;
  int l15 = lane & 15, quad = lane >> 4;

  f32x4 acc[4][4];
#pragma unroll
  for (int a = 0; a < 4; ++a)
#pragma unroll
    for (int b = 0; b < 4; ++b) acc[a][b] = (f32x4){0.f, 0.f, 0.f, 0.f};

  for (int kt = 0; kt < KLEN; kt += 64) {
    int kb = ks + kt;
    __syncthreads();
    stage2<128, 64, 256>(Ah, m0, kb, As_h, tid, NN);
    stage2<128, 64, 256>(Bh, 0, kb, Bs_h, tid, NN);
    __syncthreads();
#pragma unroll
    for (int k0 = 0; k0 < 64; k0 += 32) {
      int ch = (k0 >> 3) + quad;
      short8 a_h[4], b_h[4];
#pragma unroll
      for (int f = 0; f < 4; ++f) {
        a_h[f] = fragN<8>(As_h, wm * 64 + f * 16 + l15, ch);
        b_h[f] = fragN<8>(Bs_h, wn * 64 + f * 16 + l15, ch);
      }
#pragma unroll
      for (int fm = 0; fm < 4; ++fm)
#pragma unroll
        for (int fn = 0; fn < 4; ++fn)
          acc[fm][fn] = __builtin_amdgcn_mfma_f32_16x16x32_bf16(a_h[fm], b_h[fn], acc[fm][fn], 0, 0, 0);
    }
  }
  float* Gp = G + (size_t)sp * NN * DD;
#pragma unroll
  for (int fm = 0; fm < 4; ++fm) {
    int rb = m0 + wm * 64 + fm * 16 + quad * 4;
#pragma unroll
    for (int fn = 0; fn < 4; ++fn) {
      int c = wn * 64 + fn * 16 + l15;
#pragma unroll
      for (int i = 0; i < 4; ++i)
        Gp[(size_t)(rb + i) * DD + c] = acc[fm][fn][i];
    }
  }
}

// ---- K4/K7: Out/Z = act( d * (sum_p G_p [+ sparse]) + b ); optional zh/sq emission ----
template <int NP>
__global__ __launch_bounds__(256) void k_red(
    const float* __restrict__ G, const float* __restrict__ dvec,
    const float* __restrict__ bvec, int leaky,
    float* __restrict__ Out, unsigned short* __restrict__ zh,
    float* __restrict__ sqout,
    const float* __restrict__ Usp, const float* __restrict__ sval,
    const int* __restrict__ sidx, const void* kptr) {
  int r0 = blockIdx.x * 16;
  int tid = threadIdx.x;
  int tr = tid >> 4, tc = tid & 15;
  int r = r0 + tr;
  size_t off = (size_t)r * DD + tc * 8;
  __shared__ float red[256];

  float acc[8];
#pragma unroll
  for (int u = 0; u < 8; ++u) acc[u] = 0.f;
#pragma unroll
  for (int p = 0; p < NP; ++p) {
    const float* gp = G + (size_t)p * NN * DD + off;
    float4 g0 = *(const float4*)gp;
    float4 g1 = *(const float4*)(gp + 4);
    acc[0] += g0.x; acc[1] += g0.y; acc[2] += g0.z; acc[3] += g0.w;
    acc[4] += g1.x; acc[5] += g1.y; acc[6] += g1.z; acc[7] += g1.w;
  }
  if (sidx != nullptr) {
    int kk = dec_i(kptr); kk = kk < 1 ? 1 : (kk > 4 ? 4 : kk);
    for (int t = 0; t < kk; ++t) {
      float sv = sval[r * 8 + t];
      int id = sidx[r * 8 + t];
      const float* vr = Usp + (size_t)id * DD + tc * 8;
      float4 w0 = *(const float4*)vr;
      float4 w1 = *(const float4*)(vr + 4);
      acc[0] = fmaf(sv, w0.x, acc[0]); acc[1] = fmaf(sv, w0.y, acc[1]);
      acc[2] = fmaf(sv, w0.z, acc[2]); acc[3] = fmaf(sv, w0.w, acc[3]);
      acc[4] = fmaf(sv, w1.x, acc[4]); acc[5] = fmaf(sv, w1.y, acc[5]);
      acc[6] = fmaf(sv, w1.z, acc[6]); acc[7] = fmaf(sv, w1.w, acc[7]);
    }
  }
  float d = dvec[r];
  float4 b0 = *(const float4*)(bvec + tc * 8);
  float4 b1 = *(const float4*)(bvec + tc * 8 + 4);
  float bb[8] = {b0.x, b0.y, b0.z, b0.w, b1.x, b1.y, b1.z, b1.w};
  float o[8];
#pragma unroll
  for (int u = 0; u < 8; ++u) {
    float v = fmaf(d, acc[u], bb[u]);
    if (leaky) v = v > 0.f ? v : 0.1f * v;
    o[u] = v;
  }
  if (Out) {
    float4 o0 = {o[0], o[1], o[2], o[3]};
    float4 o1 = {o[4], o[5], o[6], o[7]};
    *(float4*)(Out + off) = o0;
    *(float4*)(Out + off + 4) = o1;
  }
  if (zh) {
    ushort4 h0 = {f2bf(o[0]), f2bf(o[1]), f2bf(o[2]), f2bf(o[3])};
    ushort4 h1 = {f2bf(o[4]), f2bf(o[5]), f2bf(o[6]), f2bf(o[7])};
    *(ushort4*)(zh + off) = h0;
    *(ushort4*)(zh + off + 4) = h1;
  }
  if (sqout != nullptr) {
    float p = 0.f;
#pragma unroll
    for (int u = 0; u < 8; ++u) p = fmaf(o[u], o[u], p);
    red[tid] = p;
    __syncthreads();
    if (tc == 0) {
      float s = 0.f;
#pragma unroll
      for (int i = 0; i < 16; ++i) s += red[tr * 16 + i];
      sqout[r] = s;
    }
  }
}

// ---- K6: MFMA bf16 Z@Z^T, fused d2-key top-4 per (row, j-slice) ----
__global__ __launch_bounds__(512, 8) void k_scores(
    const unsigned short* __restrict__ Zh,
    const float* __restrict__ sq, u64* __restrict__ pkey) {
  __shared__ __align__(16) unsigned short Am[64 * 128];   // 16 KB; merge lists alias
  __shared__ __align__(16) unsigned short Bj[64 * 128];   // 16 KB; Stile aliases
  float* Stile = (float*)&Bj[0];
  u64* mv = (u64*)&Am[0];

  int bx = blockIdx.x;
  int mt = bx >> 4, jp = bx & 15;
  int m0 = mt * 64, j0 = jp * 256;
  int tid = threadIdx.x, lane = tid & 63, w = tid >> 6;
  int wm = w >> 2, wn = w & 3;
  int l15 = lane & 15, quad = lane >> 4;

  stage2<64, 128, 512>(Zh, m0, 0, Am, tid, DD);

  int srow = tid >> 3;
  int sc = tid & 7;
  float sqi_r = sq[m0 + srow];

  u64 lst[4];
#pragma unroll
  for (int s = 0; s < 4; ++s) lst[s] = ~0ull;

  for (int jt = 0; jt < 4; ++jt) {
    int jrow0 = j0 + jt * 64;
    __syncthreads();
    stage2<64, 128, 512>(Zh, jrow0, 0, Bj, tid, DD);
    __syncthreads();

    f32x4 acc[2];
    acc[0] = (f32x4){0.f, 0.f, 0.f, 0.f};
    acc[1] = (f32x4){0.f, 0.f, 0.f, 0.f};
#pragma unroll
    for (int kc = 0; kc < 4; ++kc) {
      int ch = kc * 4 + quad;
      short8 ah0 = fragN<16>(Am, wm * 32 + l15, ch);
      short8 ah1 = fragN<16>(Am, wm * 32 + 16 + l15, ch);
      short8 bh  = fragN<16>(Bj, wn * 16 + l15, ch);
      acc[0] = __builtin_amdgcn_mfma_f32_16x16x32_bf16(ah0, bh, acc[0], 0, 0, 0);
      acc[1] = __builtin_amdgcn_mfma_f32_16x16x32_bf16(ah1, bh, acc[1], 0, 0, 0);
    }
    __syncthreads();

    {
      int c = wn * 16 + l15;
      float sqjv = sq[jrow0 + c];
      int cslot = c >> 2, cw = c & 3;
#pragma unroll
      for (int fm = 0; fm < 2; ++fm) {
        int rb = wm * 32 + fm * 16 + quad * 4;
#pragma unroll
        for (int i = 0; i < 4; ++i) {
          int r = rb + i;
          Stile[r * 64 + ((cslot ^ (r & 7)) << 2) + cw] = fmaf(-2.f, acc[fm][i], sqjv);
        }
      }
    }
    __syncthreads();

#pragma unroll
    for (int q = 0; q < 2; ++q) {
      int slot = sc * 2 + q;
      float4 kv = *(const float4*)(Stile + srow * 64 + ((slot ^ (srow & 7)) << 2));
      int jb = jrow0 + sc * 8 + q * 4;
      float ke[4] = {kv.x, kv.y, kv.z, kv.w};
#pragma unroll
      for (int e = 0; e < 4; ++e) {
        float v = fmaxf(sqi_r + ke[e], 0.f);
        ins4(lst, ((u64)__float_as_uint(v) << 32) | (unsigned)(jb + e));
      }
    }
  }

  __syncthreads();
#pragma unroll
  for (int s = 0; s < 4; ++s) mv[tid * 4 + s] = lst[s];
  __syncthreads();
  if (tid < 64) {
    u64 best[4] = {~0ull, ~0ull, ~0ull, ~0ull};
    for (int g = 0; g < 8; ++g) {
      int src = tid * 8 + g;
#pragma unroll
      for (int s = 0; s < 4; ++s) ins4(best, mv[src * 4 + s]);
    }
#pragma unroll
    for (int s = 0; s < 4; ++s)
      pkey[((size_t)(m0 + tid) * 16 + jp) * 4 + s] = best[s];
  }
}

extern "C" void kernel_launch(void* const* d_in, const int* in_sizes, int n_in,
                              void* d_out, int out_size, void* d_ws, size_t ws_size,
                              hipStream_t stream) {
  const float* x  = (const float*)d_in[0];
  const float* A  = (const float*)d_in[1];
  const float* W1 = (const float*)d_in[2];
  const float* b1 = (const float*)d_in[3];
  const float* W2 = (const float*)d_in[4];
  const float* b2 = (const float*)d_in[5];
  const void* sig = (n_in > 6) ? d_in[6] : nullptr;
  const void* kp  = (n_in > 7) ? d_in[7] : nullptr;

  float* ws = (float*)d_ws;
  float* rowsumA = ws;                                   // 4096
  float* dvec    = ws + 4096;                            // 4096
  float* d2vec   = ws + 8192;                            // 4096
  float* sqv     = ws + 12288;                           // 4096
  float* sval    = ws + 16384;                           // 32768
  int*   sidx    = (int*)(ws + 49152);                   // 32768
  u64*   pkey    = (u64*)(ws + 81920);                   // 262144 u64 = 524288 floats
  unsigned short* Zh = (unsigned short*)(ws + 606208);   // 262144 floats
  float* U       = ws + 1392640;                         // 524288
  unsigned short* UTh = (unsigned short*)(ws + 1916928); // 262144 floats
  unsigned short* Ah  = (unsigned short*)(ws + 2179072); // 8388608 floats
  float* G       = ws + 10567680;                        // SPLIT * 524288

  const size_t F16 = 10567680 + 16 * 524288;  // ~75.8 MB
  int split16 = (ws_size >= F16 * 4);

  k_rowsum_scale<<<4096, 256, 0, stream>>>(A, rowsumA, dvec, Ah);
  // pass 1: Z = leaky(d * (A @ ((d*x)@W1)) + b1), emit Zh + sq
  k_xwt<1><<<64, 256, 0, stream>>>(x, W1, dvec, nullptr, nullptr,
                                   nullptr, nullptr, nullptr, nullptr, UTh,
                                   nullptr, nullptr);
  if (split16) {
    k_gemm_bf16<16><<<512, 256, 0, stream>>>(Ah, UTh, G);
    k_red<16><<<256, 256, 0, stream>>>(G, dvec, b1, 1, nullptr, Zh, sqv,
                                       nullptr, nullptr, nullptr, nullptr);
  } else {
    k_gemm_bf16<4><<<128, 256, 0, stream>>>(Ah, UTh, G);
    k_red<4><<<256, 256, 0, stream>>>(G, dvec, b1, 1, nullptr, Zh, sqv,
                                      nullptr, nullptr, nullptr, nullptr);
  }
  // scores + top-k
  k_scores<<<1024, 512, 0, stream>>>(Zh, sqv, pkey);
  // pass 2 front-end: merge top-k -> d2, U = (d2*x)@W2, UTh
  k_xwt<2><<<64, 256, 0, stream>>>(x, W2, nullptr, pkey, rowsumA,
                                   sval, sidx, d2vec, U, UTh, kp, sig);
  if (split16) {
    k_gemm_bf16<16><<<512, 256, 0, stream>>>(Ah, UTh, G);
    k_red<16><<<256, 256, 0, stream>>>(G, d2vec, b2, 0, (float*)d_out, nullptr, nullptr,
                                       U, sval, sidx, kp);
  } else {
    k_gemm_bf16<4><<<128, 256, 0, stream>>>(Ah, UTh, G);
    k_red<4><<<256, 256, 0, stream>>>(G, d2vec, b2, 0, (float*)d_out, nullptr, nullptr,
                                      U, sval, sidx, kp);
  }
}